// Round 1
// baseline (1231.990 us; speedup 1.0000x reference)
//
#include <hip/hip_runtime.h>

// Matching pursuit via Gram-matrix incremental projection updates.
//   proj0 = X @ D                        (GEMM, once)
//   G     = D^T @ D                      (GEMM, once)
//   loop 32x: best = argmax|proj|; coef = proj[best];
//             proj -= coef * G[best,:];  codes[best] += coef
//   recon = sum_i coef_i * D[:, a_i]     (sparse, from DT rows)

#define FD 512
#define NA 4096
#define NTHREAD 256
#define PR 16  // NA / NTHREAD

#define TM 128
#define TN 128
#define TK 16
#define PADM 132

// ---------- transpose: DT[NA][FD] = D[FD][NA]^T ----------
__global__ __launch_bounds__(1024) void k_transpose(const float* __restrict__ D,
                                                    float* __restrict__ DT) {
  __shared__ float tile[32][33];
  const int bx = blockIdx.x * 32;  // atom block (cols of D)
  const int by = blockIdx.y * 32;  // feature block (rows of D)
  const int tx = threadIdx.x, ty = threadIdx.y;
  tile[ty][tx] = D[(size_t)(by + ty) * NA + bx + tx];
  __syncthreads();
  DT[(size_t)(bx + ty) * FD + by + tx] = tile[tx][ty];
}

// ---------- fp32 NN GEMM: C[M][N] = A[M][K] @ B[K][N] ----------
// 128x128 block tile, 256 threads, 8x8 micro-tile (split 4+4 halves so
// LDS fragment reads are contiguous float4 across lanes).
__global__ __launch_bounds__(256) void k_gemm_nn(const float* __restrict__ A,
                                                 const float* __restrict__ B,
                                                 float* __restrict__ C,
                                                 int M, int N, int K) {
  __shared__ float As[TK][PADM];  // transposed A tile, padded (132 keeps 16B align)
  __shared__ float Bs[TK][TN];
  const int t = threadIdx.x;
  const int tx = t & 15, ty = t >> 4;
  const int bm = blockIdx.y * TM, bn = blockIdx.x * TN;

  float acc[8][8];
#pragma unroll
  for (int i = 0; i < 8; i++)
#pragma unroll
    for (int j = 0; j < 8; j++) acc[i][j] = 0.f;

  for (int kt = 0; kt < K; kt += TK) {
// stage A tile (transposed into LDS)
#pragma unroll
    for (int i = 0; i < 2; i++) {
      const int f = t + i * 256;           // 0..511
      const int row = f >> 2;              // 0..127
      const int kc = (f & 3) * 4;          // 0,4,8,12
      const float4 v = *(const float4*)(A + (size_t)(bm + row) * K + kt + kc);
      As[kc + 0][row] = v.x;
      As[kc + 1][row] = v.y;
      As[kc + 2][row] = v.z;
      As[kc + 3][row] = v.w;
    }
// stage B tile (natural layout)
#pragma unroll
    for (int i = 0; i < 2; i++) {
      const int f = t + i * 256;
      const int kr = f >> 5;               // 0..15
      const int nc = (f & 31) * 4;         // 0..124
      *(float4*)(&Bs[kr][nc]) = *(const float4*)(B + (size_t)(kt + kr) * N + bn + nc);
    }
    __syncthreads();
#pragma unroll
    for (int k = 0; k < TK; k++) {
      float a[8], b[8];
      *(float4*)(a) = *(const float4*)(&As[k][ty * 4]);
      *(float4*)(a + 4) = *(const float4*)(&As[k][64 + ty * 4]);
      *(float4*)(b) = *(const float4*)(&Bs[k][tx * 4]);
      *(float4*)(b + 4) = *(const float4*)(&Bs[k][64 + tx * 4]);
#pragma unroll
      for (int i = 0; i < 8; i++)
#pragma unroll
        for (int j = 0; j < 8; j++) acc[i][j] = fmaf(a[i], b[j], acc[i][j]);
    }
    __syncthreads();
  }
#pragma unroll
  for (int ih = 0; ih < 2; ih++)
#pragma unroll
    for (int i = 0; i < 4; i++) {
      float* Crow = C + (size_t)(bm + ih * 64 + ty * 4 + i) * N + bn;
      *(float4*)(Crow + tx * 4) = *(float4*)(&acc[ih * 4 + i][0]);
      *(float4*)(Crow + 64 + tx * 4) = *(float4*)(&acc[ih * 4 + i][4]);
    }
}

// ---------- matching pursuit + fused recon: one workgroup per sample ----------
template <bool HAVE_PROJ>
__global__ __launch_bounds__(256) void k_mp(const float* __restrict__ X,
                                            const float* __restrict__ D,
                                            const float* __restrict__ proj_g,
                                            const float* __restrict__ G,
                                            const float* __restrict__ DT,
                                            float* __restrict__ out,
                                            const int* __restrict__ spars_p) {
  const int s = blockIdx.x;
  const int t = threadIdx.x;
  int sp = spars_p[0];
  if (sp > 64) sp = 64;
  if (sp < 0) sp = 0;

  __shared__ float red_abs[4];
  __shared__ int red_idx[4];
  __shared__ float coef_sh;
  __shared__ float xsh[FD];
  __shared__ int a_idx[64];
  __shared__ float a_coef[64];

  float p[PR];  // this thread's slice of proj: atoms r*256 + t
  if (HAVE_PROJ) {
    const float* pr = proj_g + (size_t)s * NA;
#pragma unroll
    for (int r = 0; r < PR; r++) p[r] = pr[r * NTHREAD + t];
  } else {
    for (int i = t; i < FD; i += NTHREAD) xsh[i] = X[(size_t)s * FD + i];
    __syncthreads();
#pragma unroll
    for (int r = 0; r < PR; r++) p[r] = 0.f;
    for (int k = 0; k < FD; k++) {
      const float xv = xsh[k];
      const float* Drow = D + (size_t)k * NA;
#pragma unroll
      for (int r = 0; r < PR; r++) p[r] = fmaf(xv, Drow[r * NTHREAD + t], p[r]);
    }
  }

  for (int it = 0; it < sp; it++) {
    // local argmax with first-index tie-break (jnp.argmax semantics)
    float ba = -1.f;
    int bi = 0x7fffffff;
#pragma unroll
    for (int r = 0; r < PR; r++) {
      const float av = fabsf(p[r]);
      const int idx = r * NTHREAD + t;
      if (av > ba || (av == ba && idx < bi)) {
        ba = av;
        bi = idx;
      }
    }
    // wave butterfly reduce (64 lanes)
#pragma unroll
    for (int off = 32; off > 0; off >>= 1) {
      const float oa = __shfl_xor(ba, off);
      const int oi = __shfl_xor(bi, off);
      if (oa > ba || (oa == ba && oi < bi)) {
        ba = oa;
        bi = oi;
      }
    }
    if ((t & 63) == 0) {
      red_abs[t >> 6] = ba;
      red_idx[t >> 6] = bi;
    }
    __syncthreads();
    ba = red_abs[0];
    bi = red_idx[0];
#pragma unroll
    for (int w = 1; w < 4; w++) {
      const float oa = red_abs[w];
      const int oi = red_idx[w];
      if (oa > ba || (oa == ba && oi < bi)) {
        ba = oa;
        bi = oi;
      }
    }
    const int best = bi;
    if ((best & (NTHREAD - 1)) == t) {  // unique owner thread
      const float c = p[best >> 8];
      coef_sh = c;
      a_idx[it] = best;
      a_coef[it] = c;
    }
    __syncthreads();
    const float coef = coef_sh;
    const float* Grow = G + (size_t)best * NA;
#pragma unroll
    for (int r = 0; r < PR; r++) p[r] = fmaf(-coef, Grow[r * NTHREAD + t], p[r]);
  }

  __syncthreads();
  // fused recon: out[s,:] = sum_i coef_i * DT[a_i, :]
  float2 acc = make_float2(0.f, 0.f);
  for (int it = 0; it < sp; it++) {
    const float c = a_coef[it];
    const float2 dv = *(const float2*)(DT + (size_t)a_idx[it] * FD + t * 2);
    acc.x = fmaf(c, dv.x, acc.x);
    acc.y = fmaf(c, dv.y, acc.y);
  }
  *(float2*)(out + (size_t)s * FD + t * 2) = acc;
}

extern "C" void kernel_launch(void* const* d_in, const int* in_sizes, int n_in,
                              void* d_out, int out_size, void* d_ws, size_t ws_size,
                              hipStream_t stream) {
  const float* X = (const float*)d_in[0];       // [B][512]
  const float* D = (const float*)d_in[1];       // [512][4096]
  const int* spars = (const int*)d_in[2];       // scalar
  float* out = (float*)d_out;                   // [B][512]
  const int B = in_sizes[0] / FD;               // 8192

  char* ws = (char*)d_ws;
  float* DT = (float*)ws;                                               // 8 MB
  float* G = (float*)(ws + (size_t)NA * FD * 4);                        // 64 MB
  float* proj = (float*)(ws + (size_t)NA * FD * 4 + (size_t)NA * NA * 4);  // 128 MB
  const size_t need_full =
      (size_t)NA * FD * 4 + (size_t)NA * NA * 4 + (size_t)B * NA * 4;

  k_transpose<<<dim3(NA / 32, FD / 32), dim3(32, 32), 0, stream>>>(D, DT);
  // G = DT @ D  (i.e. D^T D), M=N=4096, K=512
  k_gemm_nn<<<dim3(NA / TN, NA / TM), 256, 0, stream>>>(DT, D, G, NA, NA, FD);

  if (ws_size >= need_full) {
    // proj = X @ D, M=B, N=4096, K=512
    k_gemm_nn<<<dim3(NA / TN, B / TM), 256, 0, stream>>>(X, D, proj, B, NA, FD);
    k_mp<true><<<B, NTHREAD, 0, stream>>>(X, D, proj, G, DT, out, spars);
  } else {
    // workspace too small for proj buffer: compute proj per-block (slower GEMV)
    k_mp<false><<<B, NTHREAD, 0, stream>>>(X, D, nullptr, G, DT, out, spars);
  }
}

// Round 2
// 1181.388 us; speedup vs baseline: 1.0428x; 1.0428x over previous
//
#include <hip/hip_runtime.h>

// Matching pursuit via Gram-matrix incremental projection updates.
//   proj0 = X @ D                        (GEMM, once)
//   G     = D^T @ D                      (GEMM, once)
//   loop 32x: best = argmax|proj|; coef = proj[best];
//             proj -= coef * G[best,:]
//   recon = sum_i coef_i * DT[a_i, :]    (sparse, from DT rows)
//
// k_mp64: ONE WAVE per sample. proj row lives in p[64] registers/lane.
// Argmax via packed-u64 shfl butterfly (abs in high bits, ~((idx<<1)|sign)
// in low bits) -> every lane gets max|proj|, first-index tie-break AND the
// sign, so coef is recovered with no LDS round trip and no barriers.

#define FD 512
#define NA 4096

#define TM 128
#define TN 128
#define TK 16
#define PADM 132

// ---------- transpose: DT[NA][FD] = D[FD][NA]^T ----------
__global__ __launch_bounds__(1024) void k_transpose(const float* __restrict__ D,
                                                    float* __restrict__ DT) {
  __shared__ float tile[32][33];
  const int bx = blockIdx.x * 32;
  const int by = blockIdx.y * 32;
  const int tx = threadIdx.x, ty = threadIdx.y;
  tile[ty][tx] = D[(size_t)(by + ty) * NA + bx + tx];
  __syncthreads();
  DT[(size_t)(bx + ty) * FD + by + tx] = tile[tx][ty];
}

// ---------- fp32 NN GEMM: C[M][N] = A[M][K] @ B[K][N] ----------
__global__ __launch_bounds__(256) void k_gemm_nn(const float* __restrict__ A,
                                                 const float* __restrict__ B,
                                                 float* __restrict__ C,
                                                 int M, int N, int K) {
  __shared__ float As[TK][PADM];
  __shared__ float Bs[TK][TN];
  const int t = threadIdx.x;
  const int tx = t & 15, ty = t >> 4;
  const int bm = blockIdx.y * TM, bn = blockIdx.x * TN;

  float acc[8][8];
#pragma unroll
  for (int i = 0; i < 8; i++)
#pragma unroll
    for (int j = 0; j < 8; j++) acc[i][j] = 0.f;

  for (int kt = 0; kt < K; kt += TK) {
#pragma unroll
    for (int i = 0; i < 2; i++) {
      const int f = t + i * 256;
      const int row = f >> 2;
      const int kc = (f & 3) * 4;
      const float4 v = *(const float4*)(A + (size_t)(bm + row) * K + kt + kc);
      As[kc + 0][row] = v.x;
      As[kc + 1][row] = v.y;
      As[kc + 2][row] = v.z;
      As[kc + 3][row] = v.w;
    }
#pragma unroll
    for (int i = 0; i < 2; i++) {
      const int f = t + i * 256;
      const int kr = f >> 5;
      const int nc = (f & 31) * 4;
      *(float4*)(&Bs[kr][nc]) = *(const float4*)(B + (size_t)(kt + kr) * N + bn + nc);
    }
    __syncthreads();
#pragma unroll
    for (int k = 0; k < TK; k++) {
      float a[8], b[8];
      *(float4*)(a) = *(const float4*)(&As[k][ty * 4]);
      *(float4*)(a + 4) = *(const float4*)(&As[k][64 + ty * 4]);
      *(float4*)(b) = *(const float4*)(&Bs[k][tx * 4]);
      *(float4*)(b + 4) = *(const float4*)(&Bs[k][64 + tx * 4]);
#pragma unroll
      for (int i = 0; i < 8; i++)
#pragma unroll
        for (int j = 0; j < 8; j++) acc[i][j] = fmaf(a[i], b[j], acc[i][j]);
    }
    __syncthreads();
  }
#pragma unroll
  for (int ih = 0; ih < 2; ih++)
#pragma unroll
    for (int i = 0; i < 4; i++) {
      float* Crow = C + (size_t)(bm + ih * 64 + ty * 4 + i) * N + bn;
      *(float4*)(Crow + tx * 4) = *(float4*)(&acc[ih * 4 + i][0]);
      *(float4*)(Crow + 64 + tx * 4) = *(float4*)(&acc[ih * 4 + i][4]);
    }
}

// ---------- matching pursuit, one wave per sample ----------
// Element map: lane l, reg r = q*4+j  <->  atom idx = q*256 + l*4 + j.
template <bool HAVE_PROJ>
__global__ __launch_bounds__(64, 4) void k_mp64(const float* __restrict__ X,
                                                const float* __restrict__ D,
                                                const float* __restrict__ proj_g,
                                                const float* __restrict__ G,
                                                const float* __restrict__ DT,
                                                float* __restrict__ out,
                                                const int* __restrict__ spars_p) {
  const int s = blockIdx.x;
  const int l = threadIdx.x;  // 0..63
  int sp = spars_p[0];
  if (sp < 0) sp = 0;
  if (sp > 128) sp = 128;

  __shared__ int a_idx_sh[128];
  __shared__ float a_coef_sh[128];
  __shared__ float xsh[FD];

  float p[64];
  if (HAVE_PROJ) {
    const float4* pr = (const float4*)(proj_g + (size_t)s * NA);
#pragma unroll
    for (int q = 0; q < 16; q++) {
      const float4 v = pr[q * 64 + l];
      p[q * 4 + 0] = v.x;
      p[q * 4 + 1] = v.y;
      p[q * 4 + 2] = v.z;
      p[q * 4 + 3] = v.w;
    }
  } else {
    for (int i = l; i < FD; i += 64) xsh[i] = X[(size_t)s * FD + i];
    __syncthreads();
#pragma unroll
    for (int r = 0; r < 64; r++) p[r] = 0.f;
    for (int k = 0; k < FD; k++) {
      const float xv = xsh[k];
      const float4* Dr = (const float4*)(D + (size_t)k * NA);
#pragma unroll
      for (int q = 0; q < 16; q++) {
        const float4 dv = Dr[q * 64 + l];
        p[q * 4 + 0] = fmaf(xv, dv.x, p[q * 4 + 0]);
        p[q * 4 + 1] = fmaf(xv, dv.y, p[q * 4 + 1]);
        p[q * 4 + 2] = fmaf(xv, dv.z, p[q * 4 + 2]);
        p[q * 4 + 3] = fmaf(xv, dv.w, p[q * 4 + 3]);
      }
    }
  }

  // local argmax accumulators: abs value + payload ((idx<<1)|sign), 4-way ILP.
  // Within an accumulator elements are visited in increasing idx order, so
  // strict > keeps the first (lowest) index on ties — jnp.argmax semantics.
  float av[4];
  unsigned ap[4];
#pragma unroll
  for (int a = 0; a < 4; a++) {
    av[a] = -1.f;
    ap[a] = 0xffffffffu;
  }
#pragma unroll
  for (int q = 0; q < 16; q++) {
    const int a = q & 3;
#pragma unroll
    for (int j = 0; j < 4; j++) {
      const float f = p[q * 4 + j];
      const float af = fabsf(f);
      const unsigned pay =
          ((unsigned)(q * 256 + l * 4 + j) << 1) | (__float_as_uint(f) >> 31);
      if (af > av[a]) {
        av[a] = af;
        ap[a] = pay;
      }
    }
  }

  for (int it = 0; it < sp; it++) {
    // merge 4 accumulators (tie -> lower payload == lower idx)
    float fa = av[0];
    unsigned pa = ap[0];
#pragma unroll
    for (int a = 1; a < 4; a++) {
      if (av[a] > fa || (av[a] == fa && ap[a] < pa)) {
        fa = av[a];
        pa = ap[a];
      }
    }
    // packed key: abs bits high (non-negative float -> monotone as uint),
    // ~payload low (so max-key => min idx on abs ties)
    unsigned long long key =
        ((unsigned long long)__float_as_uint(fa) << 32) | (unsigned)(~pa);
#pragma unroll
    for (int off = 1; off < 64; off <<= 1) {
      const unsigned long long ok = __shfl_xor(key, off);
      if (ok > key) key = ok;
    }
    const unsigned pay = ~(unsigned)key;
    const int best = pay >> 1;
    const float ba = __uint_as_float((unsigned)(key >> 32));
    const float coef = (pay & 1) ? -ba : ba;  // == proj[best] exactly

    if (l == 0) {
      a_idx_sh[it] = best;
      a_coef_sh[it] = coef;
    }

    // update p -= coef * G[best,:], fused with next iteration's argmax scan
#pragma unroll
    for (int a = 0; a < 4; a++) {
      av[a] = -1.f;
      ap[a] = 0xffffffffu;
    }
    const float4* Gr = (const float4*)(G + (size_t)best * NA);
#pragma unroll
    for (int h = 0; h < 2; h++) {
      float4 g[8];
#pragma unroll
      for (int q = 0; q < 8; q++) g[q] = Gr[(h * 8 + q) * 64 + l];
#pragma unroll
      for (int q = 0; q < 8; q++) {
        const int qq = h * 8 + q;
        const int a = qq & 3;
        float f0 = fmaf(-coef, g[q].x, p[qq * 4 + 0]);
        float f1 = fmaf(-coef, g[q].y, p[qq * 4 + 1]);
        float f2 = fmaf(-coef, g[q].z, p[qq * 4 + 2]);
        float f3 = fmaf(-coef, g[q].w, p[qq * 4 + 3]);
        p[qq * 4 + 0] = f0;
        p[qq * 4 + 1] = f1;
        p[qq * 4 + 2] = f2;
        p[qq * 4 + 3] = f3;
        const unsigned base = (unsigned)(qq * 256 + l * 4) << 1;
        const float a0 = fabsf(f0), a1 = fabsf(f1), a2 = fabsf(f2), a3 = fabsf(f3);
        if (a0 > av[a]) { av[a] = a0; ap[a] = base | 0 | (__float_as_uint(f0) >> 31); }
        if (a1 > av[a]) { av[a] = a1; ap[a] = base | 2 | (__float_as_uint(f1) >> 31); }
        if (a2 > av[a]) { av[a] = a2; ap[a] = base | 4 | (__float_as_uint(f2) >> 31); }
        if (a3 > av[a]) { av[a] = a3; ap[a] = base | 6 | (__float_as_uint(f3) >> 31); }
      }
    }
  }

  __syncthreads();
  // fused recon: out[s,:] = sum_i coef_i * DT[a_i, :]
  float4 acc0 = make_float4(0.f, 0.f, 0.f, 0.f);
  float4 acc1 = make_float4(0.f, 0.f, 0.f, 0.f);
  for (int it = 0; it < sp; it++) {
    const float c = a_coef_sh[it];
    const float4* dr = (const float4*)(DT + (size_t)a_idx_sh[it] * FD);
    const float4 d0 = dr[l];
    const float4 d1 = dr[64 + l];
    acc0.x = fmaf(c, d0.x, acc0.x);
    acc0.y = fmaf(c, d0.y, acc0.y);
    acc0.z = fmaf(c, d0.z, acc0.z);
    acc0.w = fmaf(c, d0.w, acc0.w);
    acc1.x = fmaf(c, d1.x, acc1.x);
    acc1.y = fmaf(c, d1.y, acc1.y);
    acc1.z = fmaf(c, d1.z, acc1.z);
    acc1.w = fmaf(c, d1.w, acc1.w);
  }
  float4* orow = (float4*)(out + (size_t)s * FD);
  orow[l] = acc0;
  orow[64 + l] = acc1;
}

extern "C" void kernel_launch(void* const* d_in, const int* in_sizes, int n_in,
                              void* d_out, int out_size, void* d_ws, size_t ws_size,
                              hipStream_t stream) {
  const float* X = (const float*)d_in[0];  // [B][512]
  const float* D = (const float*)d_in[1];  // [512][4096]
  const int* spars = (const int*)d_in[2];  // scalar
  float* out = (float*)d_out;              // [B][512]
  const int B = in_sizes[0] / FD;          // 8192

  char* ws = (char*)d_ws;
  float* DT = (float*)ws;                                                  // 8 MB
  float* G = (float*)(ws + (size_t)NA * FD * 4);                           // 64 MB
  float* proj = (float*)(ws + (size_t)NA * FD * 4 + (size_t)NA * NA * 4);  // 128 MB
  const size_t need_full =
      (size_t)NA * FD * 4 + (size_t)NA * NA * 4 + (size_t)B * NA * 4;

  k_transpose<<<dim3(NA / 32, FD / 32), dim3(32, 32), 0, stream>>>(D, DT);
  // G = D^T D, M=N=4096, K=512
  k_gemm_nn<<<dim3(NA / TN, NA / TM), 256, 0, stream>>>(DT, D, G, NA, NA, FD);

  if (ws_size >= need_full) {
    // proj = X @ D, M=B, N=4096, K=512
    k_gemm_nn<<<dim3(NA / TN, B / TM), 256, 0, stream>>>(X, D, proj, B, NA, FD);
    k_mp64<true><<<B, 64, 0, stream>>>(X, D, proj, G, DT, out, spars);
  } else {
    k_mp64<false><<<B, 64, 0, stream>>>(X, D, nullptr, G, DT, out, spars);
  }
}

// Round 5
// 1181.213 us; speedup vs baseline: 1.0430x; 1.0001x over previous
//
#include <hip/hip_runtime.h>

// Matching pursuit via Gram-matrix incremental projection updates.
//   proj0 = X @ D                        (fp32 GEMM, bit-identical to R2)
//   G     = D^T @ D                      (fp32 GEMM, bit-identical to R2)
//   loop 32x: best = argmax|proj|; coef = proj[best]; proj -= coef*G[best,:]
//   recon = sum_i coef_i * DT[a_i, :]
//
// R5 change vs R2 (passing): cache-policy only, zero numeric change.
//  - proj is written once (GEMM) and read once (k_mp64 init): nt store + nt
//    load so its 128 MB stream doesn't evict G (64 MB, L3-resident) from L3.
//  - out store nt (16 MB, never re-read).
//  - G GEMM launched LAST so G is freshest in L2/L3 when k_mp64 starts.
// R3/R4's f16 MFMA path is dropped: two fails with bit-identical absmax
// despite different limb numerics => deterministic bug in that kernel, not
// precision. Retry MFMA later only with components isolated one at a time.

#define FD 512
#define NA 4096

typedef float f32x4 __attribute__((ext_vector_type(4)));

__device__ __forceinline__ f32x4 ntload4(const float* p) {
  return __builtin_nontemporal_load((const f32x4*)p);
}
__device__ __forceinline__ void ntstore4(float* p, f32x4 v) {
  __builtin_nontemporal_store(v, (f32x4*)p);
}

// ---------- transpose: DT[NA][FD] = D[FD][NA]^T ----------
__global__ __launch_bounds__(1024) void k_transpose(const float* __restrict__ D,
                                                    float* __restrict__ DT) {
  __shared__ float tile[32][33];
  const int bx = blockIdx.x * 32;  // atom block
  const int by = blockIdx.y * 32;  // feature block
  const int tx = threadIdx.x, ty = threadIdx.y;
  tile[ty][tx] = D[(size_t)(by + ty) * NA + bx + tx];
  __syncthreads();
  DT[(size_t)(bx + ty) * FD + by + tx] = tile[tx][ty];
}

// ---------- fp32 NN GEMM: C[M][N] = A[M][K] @ B[K][N] ----------
// Accumulation order IDENTICAL to R2's passing kernel; only the C-store
// policy is templated (nt for proj, cached for G).
template <bool NT_STORE>
__global__ __launch_bounds__(256) void k_gemm_nn(const float* __restrict__ A,
                                                 const float* __restrict__ B,
                                                 float* __restrict__ C,
                                                 int M, int N, int K) {
#define TM 128
#define TN 128
#define TK 16
#define PADM 132
  __shared__ float As[TK][PADM];
  __shared__ float Bs[TK][TN];
  const int t = threadIdx.x;
  const int tx = t & 15, ty = t >> 4;
  const int bm = blockIdx.y * TM, bn = blockIdx.x * TN;
  float acc[8][8];
#pragma unroll
  for (int i = 0; i < 8; i++)
#pragma unroll
    for (int j = 0; j < 8; j++) acc[i][j] = 0.f;
  for (int kt = 0; kt < K; kt += TK) {
#pragma unroll
    for (int i = 0; i < 2; i++) {
      const int f = t + i * 256;
      const int row = f >> 2;
      const int kc = (f & 3) * 4;
      const float4 v = *(const float4*)(A + (size_t)(bm + row) * K + kt + kc);
      As[kc + 0][row] = v.x;
      As[kc + 1][row] = v.y;
      As[kc + 2][row] = v.z;
      As[kc + 3][row] = v.w;
    }
#pragma unroll
    for (int i = 0; i < 2; i++) {
      const int f = t + i * 256;
      const int kr = f >> 5;
      const int nc = (f & 31) * 4;
      *(float4*)(&Bs[kr][nc]) = *(const float4*)(B + (size_t)(kt + kr) * N + bn + nc);
    }
    __syncthreads();
#pragma unroll
    for (int k = 0; k < TK; k++) {
      float a[8], b[8];
      *(float4*)(a) = *(const float4*)(&As[k][ty * 4]);
      *(float4*)(a + 4) = *(const float4*)(&As[k][64 + ty * 4]);
      *(float4*)(b) = *(const float4*)(&Bs[k][tx * 4]);
      *(float4*)(b + 4) = *(const float4*)(&Bs[k][64 + tx * 4]);
#pragma unroll
      for (int i = 0; i < 8; i++)
#pragma unroll
        for (int j = 0; j < 8; j++) acc[i][j] = fmaf(a[i], b[j], acc[i][j]);
    }
    __syncthreads();
  }
#pragma unroll
  for (int ih = 0; ih < 2; ih++)
#pragma unroll
    for (int i = 0; i < 4; i++) {
      float* Crow = C + (size_t)(bm + ih * 64 + ty * 4 + i) * N + bn;
      if (NT_STORE) {
        ntstore4(Crow + tx * 4, *(const f32x4*)&acc[ih * 4 + i][0]);
        ntstore4(Crow + 64 + tx * 4, *(const f32x4*)&acc[ih * 4 + i][4]);
      } else {
        *(float4*)(Crow + tx * 4) = *(float4*)(&acc[ih * 4 + i][0]);
        *(float4*)(Crow + 64 + tx * 4) = *(float4*)(&acc[ih * 4 + i][4]);
      }
    }
}

// ---------- matching pursuit, one wave per sample ----------
// Math bit-identical to R2's passing k_mp64; proj load and out store are
// non-temporal so the 144 MB one-shot streams don't evict G from L3.
template <bool HAVE_PROJ>
__global__ __launch_bounds__(64, 4) void k_mp64(const float* __restrict__ X,
                                                const float* __restrict__ D,
                                                const float* __restrict__ proj_g,
                                                const float* __restrict__ G,
                                                const float* __restrict__ DT,
                                                float* __restrict__ out,
                                                const int* __restrict__ spars_p) {
  const int s = blockIdx.x;
  const int l = threadIdx.x;
  int sp = spars_p[0];
  if (sp < 0) sp = 0;
  if (sp > 128) sp = 128;

  __shared__ int a_idx_sh[128];
  __shared__ float a_coef_sh[128];
  __shared__ float xsh[FD];

  float p[64];
  if (HAVE_PROJ) {
    const float* pr = proj_g + (size_t)s * NA;
#pragma unroll
    for (int q = 0; q < 16; q++) {
      const f32x4 v = ntload4(pr + (q * 64 + l) * 4);
      p[q * 4 + 0] = v[0];
      p[q * 4 + 1] = v[1];
      p[q * 4 + 2] = v[2];
      p[q * 4 + 3] = v[3];
    }
  } else {
    for (int i = l; i < FD; i += 64) xsh[i] = X[(size_t)s * FD + i];
    __syncthreads();
#pragma unroll
    for (int r = 0; r < 64; r++) p[r] = 0.f;
    for (int k = 0; k < FD; k++) {
      const float xv = xsh[k];
      const float4* Dr = (const float4*)(D + (size_t)k * NA);
#pragma unroll
      for (int q = 0; q < 16; q++) {
        const float4 dv = Dr[q * 64 + l];
        p[q * 4 + 0] = fmaf(xv, dv.x, p[q * 4 + 0]);
        p[q * 4 + 1] = fmaf(xv, dv.y, p[q * 4 + 1]);
        p[q * 4 + 2] = fmaf(xv, dv.z, p[q * 4 + 2]);
        p[q * 4 + 3] = fmaf(xv, dv.w, p[q * 4 + 3]);
      }
    }
  }

  // local argmax accumulators: abs value + payload ((idx<<1)|sign), 4-way ILP.
  float av[4];
  unsigned ap[4];
#pragma unroll
  for (int a = 0; a < 4; a++) {
    av[a] = -1.f;
    ap[a] = 0xffffffffu;
  }
#pragma unroll
  for (int q = 0; q < 16; q++) {
    const int a = q & 3;
#pragma unroll
    for (int j = 0; j < 4; j++) {
      const float f = p[q * 4 + j];
      const float af = fabsf(f);
      const unsigned pay =
          ((unsigned)(q * 256 + l * 4 + j) << 1) | (__float_as_uint(f) >> 31);
      if (af > av[a]) {
        av[a] = af;
        ap[a] = pay;
      }
    }
  }

  for (int it = 0; it < sp; it++) {
    float fa = av[0];
    unsigned pa = ap[0];
#pragma unroll
    for (int a = 1; a < 4; a++) {
      if (av[a] > fa || (av[a] == fa && ap[a] < pa)) {
        fa = av[a];
        pa = ap[a];
      }
    }
    // packed key: abs bits high, ~payload low (max-key => min idx on ties)
    unsigned long long key =
        ((unsigned long long)__float_as_uint(fa) << 32) | (unsigned)(~pa);
#pragma unroll
    for (int off = 1; off < 64; off <<= 1) {
      const unsigned long long ok = __shfl_xor(key, off);
      if (ok > key) key = ok;
    }
    const unsigned pay = ~(unsigned)key;
    const int best = pay >> 1;
    const float ba = __uint_as_float((unsigned)(key >> 32));
    const float coef = (pay & 1) ? -ba : ba;  // == proj[best] exactly

    if (l == 0) {
      a_idx_sh[it] = best;
      a_coef_sh[it] = coef;
    }

    // update p -= coef * G[best,:], fused with next iteration's argmax scan
#pragma unroll
    for (int a = 0; a < 4; a++) {
      av[a] = -1.f;
      ap[a] = 0xffffffffu;
    }
    const float4* Gr = (const float4*)(G + (size_t)best * NA);
#pragma unroll
    for (int h = 0; h < 2; h++) {
      float4 g[8];
#pragma unroll
      for (int q = 0; q < 8; q++) g[q] = Gr[(h * 8 + q) * 64 + l];
#pragma unroll
      for (int q = 0; q < 8; q++) {
        const int qq = h * 8 + q;
        const int a = qq & 3;
        float f0 = fmaf(-coef, g[q].x, p[qq * 4 + 0]);
        float f1 = fmaf(-coef, g[q].y, p[qq * 4 + 1]);
        float f2 = fmaf(-coef, g[q].z, p[qq * 4 + 2]);
        float f3 = fmaf(-coef, g[q].w, p[qq * 4 + 3]);
        p[qq * 4 + 0] = f0;
        p[qq * 4 + 1] = f1;
        p[qq * 4 + 2] = f2;
        p[qq * 4 + 3] = f3;
        const unsigned base = (unsigned)(qq * 256 + l * 4) << 1;
        const float a0 = fabsf(f0), a1 = fabsf(f1), a2 = fabsf(f2), a3 = fabsf(f3);
        if (a0 > av[a]) { av[a] = a0; ap[a] = base | 0 | (__float_as_uint(f0) >> 31); }
        if (a1 > av[a]) { av[a] = a1; ap[a] = base | 2 | (__float_as_uint(f1) >> 31); }
        if (a2 > av[a]) { av[a] = a2; ap[a] = base | 4 | (__float_as_uint(f2) >> 31); }
        if (a3 > av[a]) { av[a] = a3; ap[a] = base | 6 | (__float_as_uint(f3) >> 31); }
      }
    }
  }

  __syncthreads();
  // fused recon: out[s,:] = sum_i coef_i * DT[a_i, :]
  float4 acc0 = make_float4(0.f, 0.f, 0.f, 0.f);
  float4 acc1 = make_float4(0.f, 0.f, 0.f, 0.f);
  for (int it = 0; it < sp; it++) {
    const float c = a_coef_sh[it];
    const float4* dr = (const float4*)(DT + (size_t)a_idx_sh[it] * FD);
    const float4 d0 = dr[l];
    const float4 d1 = dr[64 + l];
    acc0.x = fmaf(c, d0.x, acc0.x);
    acc0.y = fmaf(c, d0.y, acc0.y);
    acc0.z = fmaf(c, d0.z, acc0.z);
    acc0.w = fmaf(c, d0.w, acc0.w);
    acc1.x = fmaf(c, d1.x, acc1.x);
    acc1.y = fmaf(c, d1.y, acc1.y);
    acc1.z = fmaf(c, d1.z, acc1.z);
    acc1.w = fmaf(c, d1.w, acc1.w);
  }
  float* orow = out + (size_t)s * FD;
  ntstore4(orow + l * 4, (f32x4){acc0.x, acc0.y, acc0.z, acc0.w});
  ntstore4(orow + 256 + l * 4, (f32x4){acc1.x, acc1.y, acc1.z, acc1.w});
}

extern "C" void kernel_launch(void* const* d_in, const int* in_sizes, int n_in,
                              void* d_out, int out_size, void* d_ws, size_t ws_size,
                              hipStream_t stream) {
  const float* X = (const float*)d_in[0];  // [B][512]
  const float* D = (const float*)d_in[1];  // [512][4096]
  const int* spars = (const int*)d_in[2];  // scalar
  float* out = (float*)d_out;              // [B][512]
  const int B = in_sizes[0] / FD;          // 8192

  char* ws = (char*)d_ws;
  const size_t szDT = (size_t)NA * FD * 4;   // 8 MB
  const size_t szG = (size_t)NA * NA * 4;    // 64 MB
  const size_t szProj = (size_t)B * NA * 4;  // 128 MB

  float* DT = (float*)ws;
  float* G = (float*)(ws + szDT);
  float* proj = (float*)(ws + szDT + szG);
  const size_t need_full = szDT + szG + szProj;  // 200 MB

  k_transpose<<<dim3(NA / 32, FD / 32), dim3(32, 32), 0, stream>>>(D, DT);

  if (ws_size >= need_full) {
    // proj = X @ D first (nt store: don't thrash L3), then G = D^T D last
    // (normal store: G should be resident in L2/L3 when k_mp64 starts).
    k_gemm_nn<true><<<dim3(NA / TN, B / TM), 256, 0, stream>>>(X, D, proj, B, NA, FD);
    k_gemm_nn<false><<<dim3(NA / TN, NA / TM), 256, 0, stream>>>(DT, D, G, NA, NA, FD);
    k_mp64<true><<<B, 64, 0, stream>>>(X, D, proj, G, DT, out, spars);
  } else {
    k_gemm_nn<false><<<dim3(NA / TN, NA / TM), 256, 0, stream>>>(DT, D, G, NA, NA, FD);
    k_mp64<false><<<B, 64, 0, stream>>>(X, D, nullptr, G, DT, out, spars);
  }
}

// Round 6
// 1173.986 us; speedup vs baseline: 1.0494x; 1.0062x over previous
//
#include <hip/hip_runtime.h>

// Matching pursuit via Gram-matrix incremental projection updates.
//   proj0 = X @ D            (fp32 GEMM, packed v_pk_fma_f32, bitwise = R2)
//   G     = D^T @ D          (fp32 GEMM, upper-triangle 128-blocks + mirror)
//   loop 32x: best = argmax|proj|; coef = proj[best]; proj -= coef*G[best,:]
//   recon = sum_i coef_i * DT[a_i, :]
//
// All changes vs R5 (passing) are bitwise-exact:
//  - f32x2 packed FMA pairs two INDEPENDENT output accumulators per
//    instruction; each output's k-ascending fma chain is unchanged.
//  - G[j][i] := G[i][j] mirror: same dot product, same k-order, operands
//    swapped (fma(a,b,c)==fma(b,a,c)) -> bitwise identical G.
//  - k_mp64 untouched.
// Numerics margin is ~1e-7 (R3/R4 post-mortem): no non-bitwise changes.

#define FD 512
#define NA 4096

#define TM 128
#define TN 128
#define TK 16
#define PADM 132

typedef float f32x4 __attribute__((ext_vector_type(4)));
typedef float f32x2 __attribute__((ext_vector_type(2)));

__device__ __forceinline__ f32x4 ntload4(const float* p) {
  return __builtin_nontemporal_load((const f32x4*)p);
}
__device__ __forceinline__ void ntstore4(float* p, f32x4 v) {
  __builtin_nontemporal_store(v, (f32x4*)p);
}

// ---------- transpose: DT[NA][FD] = D[FD][NA]^T ----------
__global__ __launch_bounds__(1024) void k_transpose(const float* __restrict__ D,
                                                    float* __restrict__ DT) {
  __shared__ float tile[32][33];
  const int bx = blockIdx.x * 32;  // atom block
  const int by = blockIdx.y * 32;  // feature block
  const int tx = threadIdx.x, ty = threadIdx.y;
  tile[ty][tx] = D[(size_t)(by + ty) * NA + bx + tx];
  __syncthreads();
  DT[(size_t)(bx + ty) * FD + by + tx] = tile[tx][ty];
}

// ---------- mirror: fill strictly-lower 128-blocks of G from upper ----------
__global__ __launch_bounds__(1024) void k_mirror(float* __restrict__ G) {
  const int bx = blockIdx.x, by = blockIdx.y;  // target 32-tile (rows bx*32, cols by*32)
  if ((bx >> 2) <= (by >> 2)) return;          // only strictly-lower 128-blocks
  __shared__ float tile[32][33];
  const int tx = threadIdx.x, ty = threadIdx.y;
  // source tile (upper, computed): rows by*32.., cols bx*32..
  tile[ty][tx] = G[(size_t)(by * 32 + ty) * NA + bx * 32 + tx];
  __syncthreads();
  G[(size_t)(bx * 32 + ty) * NA + by * 32 + tx] = tile[tx][ty];
}

// ---------- fp32 NN GEMM: C[M][N] = A[M][K] @ B[K][N] ----------
// Same tiling/staging/k-order as the R2-passing kernel; inner loop packed
// into f32x2 (v_pk_fma_f32). TRIANGLE: skip blocks with bn-block < bm-block.
template <bool NT_STORE, bool TRIANGLE>
__global__ __launch_bounds__(256) void k_gemm_nn(const float* __restrict__ A,
                                                 const float* __restrict__ B,
                                                 float* __restrict__ C,
                                                 int M, int N, int K) {
  if (TRIANGLE && (int)blockIdx.x < (int)blockIdx.y) return;
  __shared__ float As[TK][PADM];
  __shared__ float Bs[TK][TN];
  const int t = threadIdx.x;
  const int tx = t & 15, ty = t >> 4;
  const int bm = blockIdx.y * TM, bn = blockIdx.x * TN;

  f32x2 acc2[8][4];
#pragma unroll
  for (int i = 0; i < 8; i++)
#pragma unroll
    for (int j = 0; j < 4; j++) acc2[i][j] = (f32x2){0.f, 0.f};

  for (int kt = 0; kt < K; kt += TK) {
#pragma unroll
    for (int i = 0; i < 2; i++) {
      const int f = t + i * 256;
      const int row = f >> 2;
      const int kc = (f & 3) * 4;
      const float4 v = *(const float4*)(A + (size_t)(bm + row) * K + kt + kc);
      As[kc + 0][row] = v.x;
      As[kc + 1][row] = v.y;
      As[kc + 2][row] = v.z;
      As[kc + 3][row] = v.w;
    }
#pragma unroll
    for (int i = 0; i < 2; i++) {
      const int f = t + i * 256;
      const int kr = f >> 5;
      const int nc = (f & 31) * 4;
      *(float4*)(&Bs[kr][nc]) = *(const float4*)(B + (size_t)(kt + kr) * N + bn + nc);
    }
    __syncthreads();
#pragma unroll
    for (int k = 0; k < TK; k++) {
      float a[8];
      f32x2 b2[4];
      *(float4*)(a) = *(const float4*)(&As[k][ty * 4]);
      *(float4*)(a + 4) = *(const float4*)(&As[k][64 + ty * 4]);
      {
        const f32x2* bp0 = (const f32x2*)(&Bs[k][tx * 4]);
        const f32x2* bp1 = (const f32x2*)(&Bs[k][64 + tx * 4]);
        b2[0] = bp0[0];
        b2[1] = bp0[1];
        b2[2] = bp1[0];
        b2[3] = bp1[1];
      }
#pragma unroll
      for (int i = 0; i < 8; i++) {
        const f32x2 ai = (f32x2){a[i], a[i]};
#pragma unroll
        for (int j = 0; j < 4; j++)
          acc2[i][j] = __builtin_elementwise_fma(ai, b2[j], acc2[i][j]);
      }
    }
    __syncthreads();
  }
#pragma unroll
  for (int ih = 0; ih < 2; ih++)
#pragma unroll
    for (int i = 0; i < 4; i++) {
      float* Crow = C + (size_t)(bm + ih * 64 + ty * 4 + i) * N + bn;
      const f32x4 lo = *(const f32x4*)(&acc2[ih * 4 + i][0]);
      const f32x4 hi = *(const f32x4*)(&acc2[ih * 4 + i][2]);
      if (NT_STORE) {
        ntstore4(Crow + tx * 4, lo);
        ntstore4(Crow + 64 + tx * 4, hi);
      } else {
        *(f32x4*)(Crow + tx * 4) = lo;
        *(f32x4*)(Crow + 64 + tx * 4) = hi;
      }
    }
}

// ---------- matching pursuit, one wave per sample (bit-identical to R5) ----------
template <bool HAVE_PROJ>
__global__ __launch_bounds__(64, 4) void k_mp64(const float* __restrict__ X,
                                                const float* __restrict__ D,
                                                const float* __restrict__ proj_g,
                                                const float* __restrict__ G,
                                                const float* __restrict__ DT,
                                                float* __restrict__ out,
                                                const int* __restrict__ spars_p) {
  const int s = blockIdx.x;
  const int l = threadIdx.x;
  int sp = spars_p[0];
  if (sp < 0) sp = 0;
  if (sp > 128) sp = 128;

  __shared__ int a_idx_sh[128];
  __shared__ float a_coef_sh[128];
  __shared__ float xsh[FD];

  float p[64];
  if (HAVE_PROJ) {
    const float* pr = proj_g + (size_t)s * NA;
#pragma unroll
    for (int q = 0; q < 16; q++) {
      const f32x4 v = ntload4(pr + (q * 64 + l) * 4);
      p[q * 4 + 0] = v[0];
      p[q * 4 + 1] = v[1];
      p[q * 4 + 2] = v[2];
      p[q * 4 + 3] = v[3];
    }
  } else {
    for (int i = l; i < FD; i += 64) xsh[i] = X[(size_t)s * FD + i];
    __syncthreads();
#pragma unroll
    for (int r = 0; r < 64; r++) p[r] = 0.f;
    for (int k = 0; k < FD; k++) {
      const float xv = xsh[k];
      const float4* Dr = (const float4*)(D + (size_t)k * NA);
#pragma unroll
      for (int q = 0; q < 16; q++) {
        const float4 dv = Dr[q * 64 + l];
        p[q * 4 + 0] = fmaf(xv, dv.x, p[q * 4 + 0]);
        p[q * 4 + 1] = fmaf(xv, dv.y, p[q * 4 + 1]);
        p[q * 4 + 2] = fmaf(xv, dv.z, p[q * 4 + 2]);
        p[q * 4 + 3] = fmaf(xv, dv.w, p[q * 4 + 3]);
      }
    }
  }

  // local argmax accumulators: abs value + payload ((idx<<1)|sign), 4-way ILP.
  float av[4];
  unsigned ap[4];
#pragma unroll
  for (int a = 0; a < 4; a++) {
    av[a] = -1.f;
    ap[a] = 0xffffffffu;
  }
#pragma unroll
  for (int q = 0; q < 16; q++) {
    const int a = q & 3;
#pragma unroll
    for (int j = 0; j < 4; j++) {
      const float f = p[q * 4 + j];
      const float af = fabsf(f);
      const unsigned pay =
          ((unsigned)(q * 256 + l * 4 + j) << 1) | (__float_as_uint(f) >> 31);
      if (af > av[a]) {
        av[a] = af;
        ap[a] = pay;
      }
    }
  }

  for (int it = 0; it < sp; it++) {
    float fa = av[0];
    unsigned pa = ap[0];
#pragma unroll
    for (int a = 1; a < 4; a++) {
      if (av[a] > fa || (av[a] == fa && ap[a] < pa)) {
        fa = av[a];
        pa = ap[a];
      }
    }
    // packed key: abs bits high, ~payload low (max-key => min idx on ties)
    unsigned long long key =
        ((unsigned long long)__float_as_uint(fa) << 32) | (unsigned)(~pa);
#pragma unroll
    for (int off = 1; off < 64; off <<= 1) {
      const unsigned long long ok = __shfl_xor(key, off);
      if (ok > key) key = ok;
    }
    const unsigned pay = ~(unsigned)key;
    const int best = pay >> 1;
    const float ba = __uint_as_float((unsigned)(key >> 32));
    const float coef = (pay & 1) ? -ba : ba;  // == proj[best] exactly

    if (l == 0) {
      a_idx_sh[it] = best;
      a_coef_sh[it] = coef;
    }

    // update p -= coef * G[best,:], fused with next iteration's argmax scan
#pragma unroll
    for (int a = 0; a < 4; a++) {
      av[a] = -1.f;
      ap[a] = 0xffffffffu;
    }
    const float4* Gr = (const float4*)(G + (size_t)best * NA);
#pragma unroll
    for (int h = 0; h < 2; h++) {
      float4 g[8];
#pragma unroll
      for (int q = 0; q < 8; q++) g[q] = Gr[(h * 8 + q) * 64 + l];
#pragma unroll
      for (int q = 0; q < 8; q++) {
        const int qq = h * 8 + q;
        const int a = qq & 3;
        float f0 = fmaf(-coef, g[q].x, p[qq * 4 + 0]);
        float f1 = fmaf(-coef, g[q].y, p[qq * 4 + 1]);
        float f2 = fmaf(-coef, g[q].z, p[qq * 4 + 2]);
        float f3 = fmaf(-coef, g[q].w, p[qq * 4 + 3]);
        p[qq * 4 + 0] = f0;
        p[qq * 4 + 1] = f1;
        p[qq * 4 + 2] = f2;
        p[qq * 4 + 3] = f3;
        const unsigned base = (unsigned)(qq * 256 + l * 4) << 1;
        const float a0 = fabsf(f0), a1 = fabsf(f1), a2 = fabsf(f2), a3 = fabsf(f3);
        if (a0 > av[a]) { av[a] = a0; ap[a] = base | 0 | (__float_as_uint(f0) >> 31); }
        if (a1 > av[a]) { av[a] = a1; ap[a] = base | 2 | (__float_as_uint(f1) >> 31); }
        if (a2 > av[a]) { av[a] = a2; ap[a] = base | 4 | (__float_as_uint(f2) >> 31); }
        if (a3 > av[a]) { av[a] = a3; ap[a] = base | 6 | (__float_as_uint(f3) >> 31); }
      }
    }
  }

  __syncthreads();
  // fused recon: out[s,:] = sum_i coef_i * DT[a_i, :]
  float4 acc0 = make_float4(0.f, 0.f, 0.f, 0.f);
  float4 acc1 = make_float4(0.f, 0.f, 0.f, 0.f);
  for (int it = 0; it < sp; it++) {
    const float c = a_coef_sh[it];
    const float4* dr = (const float4*)(DT + (size_t)a_idx_sh[it] * FD);
    const float4 d0 = dr[l];
    const float4 d1 = dr[64 + l];
    acc0.x = fmaf(c, d0.x, acc0.x);
    acc0.y = fmaf(c, d0.y, acc0.y);
    acc0.z = fmaf(c, d0.z, acc0.z);
    acc0.w = fmaf(c, d0.w, acc0.w);
    acc1.x = fmaf(c, d1.x, acc1.x);
    acc1.y = fmaf(c, d1.y, acc1.y);
    acc1.z = fmaf(c, d1.z, acc1.z);
    acc1.w = fmaf(c, d1.w, acc1.w);
  }
  float* orow = out + (size_t)s * FD;
  ntstore4(orow + l * 4, (f32x4){acc0.x, acc0.y, acc0.z, acc0.w});
  ntstore4(orow + 256 + l * 4, (f32x4){acc1.x, acc1.y, acc1.z, acc1.w});
}

extern "C" void kernel_launch(void* const* d_in, const int* in_sizes, int n_in,
                              void* d_out, int out_size, void* d_ws, size_t ws_size,
                              hipStream_t stream) {
  const float* X = (const float*)d_in[0];  // [B][512]
  const float* D = (const float*)d_in[1];  // [512][4096]
  const int* spars = (const int*)d_in[2];  // scalar
  float* out = (float*)d_out;              // [B][512]
  const int B = in_sizes[0] / FD;          // 8192

  char* ws = (char*)d_ws;
  const size_t szDT = (size_t)NA * FD * 4;   // 8 MB
  const size_t szG = (size_t)NA * NA * 4;    // 64 MB
  const size_t szProj = (size_t)B * NA * 4;  // 128 MB

  float* DT = (float*)ws;
  float* G = (float*)(ws + szDT);
  float* proj = (float*)(ws + szDT + szG);
  const size_t need_full = szDT + szG + szProj;  // 200 MB

  k_transpose<<<dim3(NA / 32, FD / 32), dim3(32, 32), 0, stream>>>(D, DT);

  if (ws_size >= need_full) {
    // proj = X @ D (nt store), then G = D^T D upper-triangle + mirror (so G
    // is freshest in cache when k_mp64 starts).
    k_gemm_nn<true, false><<<dim3(NA / TN, B / TM), 256, 0, stream>>>(X, D, proj, B, NA, FD);
    k_gemm_nn<false, true><<<dim3(NA / TN, NA / TM), 256, 0, stream>>>(DT, D, G, NA, NA, FD);
    k_mirror<<<dim3(NA / 32, NA / 32), dim3(32, 32), 0, stream>>>(G);
    k_mp64<true><<<B, 64, 0, stream>>>(X, D, proj, G, DT, out, spars);
  } else {
    k_gemm_nn<false, true><<<dim3(NA / TN, NA / TM), 256, 0, stream>>>(DT, D, G, NA, NA, FD);
    k_mirror<<<dim3(NA / 32, NA / 32), dim3(32, 32), 0, stream>>>(G);
    k_mp64<false><<<B, 64, 0, stream>>>(X, D, nullptr, G, DT, out, spars);
  }
}